// Round 3
// baseline (203.492 us; speedup 1.0000x reference)
//
#include <hip/hip_runtime.h>
#include <hip/hip_bf16.h>

#define GLOBAL_AS __attribute__((address_space(1)))
#define LDS_AS    __attribute__((address_space(3)))

typedef __bf16 bf16x8 __attribute__((ext_vector_type(8)));
typedef float  f32x4  __attribute__((ext_vector_type(4)));

constexpr int BATCH = 8192;           // M
constexpr int IN    = 1024;
constexpr int OUT   = 1024;           // N
constexpr int KDIM  = IN * 4;         // 4096 (4 "powers" per input)
constexpr int BM = 128, BN = 256, BK = 64;
constexpr int NKT  = KDIM / BK;       // 64 K-tiles
constexpr int LDSBUF = 24576;         // ushort elems per buffer: A 8192 + B 16384 (48 KB)

// round-to-nearest-even float -> bf16 bits (inputs finite)
__device__ __forceinline__ unsigned short f2bf(float f) {
    union { float f; unsigned u; } v; v.f = f;
    unsigned r = v.u + 0x7fffu + ((v.u >> 16) & 1u);
    return (unsigned short)(r >> 16);
}
__device__ __forceinline__ unsigned pk(unsigned short a, unsigned short b) {
    return (unsigned)a | ((unsigned)b << 16);
}

// B-side prep only (A-expansion is now fused into the gemm).
// B_big[o, 4i+k] = {W[o,i], C[o,i,1..3]} bf16; be[o] = bias[o] + sum_i C[o,i,0].
__global__ __launch_bounds__(256) void prep_b(const float* __restrict__ W,
                                              const float* __restrict__ C,
                                              const float* __restrict__ bias,
                                              unsigned short* __restrict__ Bb,
                                              float* __restrict__ be) {
    const int o = blockIdx.x, t = threadIdx.x;
    const int i0 = t * 4;
    const float4* c4 = reinterpret_cast<const float4*>(C + ((size_t)o * IN + i0) * 4);
    float4 w4 = *reinterpret_cast<const float4*>(W + (size_t)o * IN + i0);
    float wv[4] = {w4.x, w4.y, w4.z, w4.w};
    float s = 0.f;
    unsigned d[8];
#pragma unroll
    for (int j = 0; j < 4; ++j) {
        float4 c = c4[j];
        s += c.x;                                  // x^0 term -> bias
        d[2*j]   = pk(f2bf(wv[j]), f2bf(c.y));
        d[2*j+1] = pk(f2bf(c.z),   f2bf(c.w));
    }
    uint4* dst = reinterpret_cast<uint4*>(Bb + (size_t)o * KDIM + i0 * 4);
    dst[0] = make_uint4(d[0], d[1], d[2], d[3]);
    dst[1] = make_uint4(d[4], d[5], d[6], d[7]);
#pragma unroll
    for (int off = 32; off > 0; off >>= 1) s += __shfl_down(s, off, 64);
    __shared__ float red[4];
    if ((t & 63) == 0) red[t >> 6] = s;
    __syncthreads();
    if (t == 0) be[o] = bias[o] + red[0] + red[1] + red[2] + red[3];
}

// Fused KAN GEMM: C = powers(x)(8192x4096) * B_big(1024x4096)^T + be.
// A-tiles are built IN-KERNEL: per K-tile each thread loads one float4 of raw x,
// computes {silu, x, x^2, x^3} (identical arithmetic to the old prep), and
// ds_write_b128's them into the XOR-swizzled LDS layout (slot = chunk ^ (row&7))
// -- byte-identical to what global_load_lds staged before, so the fragment-read
// and MFMA code is untouched. B stays on the gload_lds path (4 loads/tile).
// Triple-buffered LDS, counted vmcnt(4) boundary, setprio around MFMA clusters.
//
// Cross-wave ds_write visibility: main-loop STAGE_A writers drain via their own
// post-barrier lgkmcnt(0) BEFORE the tile-boundary barrier; readers touch that
// buffer only after crossing that barrier (2 tiles later). The PROLOGUE needs an
// explicit lgkmcnt(0) before its barrier (raw s_barrier does not drain LDS ops).
__global__ __launch_bounds__(512, 2) void gemm_kan(
        const float* __restrict__ x,
        const unsigned short* __restrict__ Bb,
        const float* __restrict__ be,
        float* __restrict__ out) {
    extern __shared__ unsigned short smem[];   // 3 * 24576 ushorts = 144 KB

    const int t    = threadIdx.x;
    const int l    = blockIdx.x;               // 0..255
    const int xcd  = l & 7;
    const int bn   = xcd >> 1;                 // 0..3  (B-panel L2-resident per XCD pair)
    const int bm   = (xcd & 1) * 32 + (l >> 3);// 0..63
    const int lane = t & 63;
    const int wave = t >> 6;                   // 0..7
    const int wr   = wave >> 2;                // 0..1 : M half
    const int wc   = wave & 3;                 // 0..3 : N quarter
    const int l15  = lane & 15;
    const int quad = lane >> 4;
    const int x7   = l15 & 7;

    // ---- B staging (gload_lds, pre-swizzled global source)
    const int rowT = t >> 3;                   // 0..63
    const int chT  = (t & 7) ^ (rowT & 7);
    const unsigned short* bS = Bb + (size_t)(bn * BN + rowT) * KDIM + chT * 8;

    // ---- A staging (reg -> swizzled ds_write): thread t owns row t>>2, x-quad t&3
    const int arow   = t >> 2;                 // 0..127
    const int axi    = t & 3;                  // which 4 of the 16 x's in the tile
    const int aoff0  = arow * 64 + (((axi * 2)     ^ (arow & 7)) * 8);
    const int aoff1  = arow * 64 + (((axi * 2 + 1) ^ (arow & 7)) * 8);
    const float4* xp = reinterpret_cast<const float4*>(
        x + (size_t)(bm * BM + arow) * IN + axi * 4);   // tile kt -> xp[kt*4]

    // ---- ds_read bases (ushort elements)
    const int aRd = (wr * 32 + l15) * 64;            // A region at offset 0
    const int bRd = 8192 + (wc * 64 + l15) * 64;     // B region at offset 8192
    const int ck0 = (quad ^ x7) * 8;
    const int ck1 = ((4 + quad) ^ x7) * 8;

    f32x4 acc[4][4];
    const f32x4 zero = {0.f, 0.f, 0.f, 0.f};
#pragma unroll
    for (int i = 0; i < 4; ++i)
#pragma unroll
        for (int j = 0; j < 4; ++j) acc[i][j] = zero;

#define STAGE_B(tile, buf, h) do {                                                     \
    const unsigned short* s_ = bS + (size_t)(tile) * BK + (size_t)(h) * 128 * KDIM;    \
    unsigned short* d_ = smem + (buf) * LDSBUF + 8192 + (h) * 8192 + t * 8;            \
    __builtin_amdgcn_global_load_lds((const GLOBAL_AS void*)s_, (LDS_AS void*)d_,      \
                                     16, 0, 0);                                        \
    __builtin_amdgcn_global_load_lds((const GLOBAL_AS void*)(s_ + (size_t)64 * KDIM),  \
                                     (LDS_AS void*)(d_ + 4096), 16, 0, 0);             \
} while (0)

    // identical arithmetic to the old prep-A (absmax must not change)
#define STAGE_A(buf, v) do {                                                           \
    float e_[4] = {(v).x, (v).y, (v).z, (v).w};                                        \
    unsigned short o_[16];                                                             \
    _Pragma("unroll")                                                                  \
    for (int j = 0; j < 4; ++j) {                                                      \
        float xv_ = e_[j];                                                             \
        float s_  = xv_ / (1.0f + __expf(-xv_));                                       \
        float x2_ = xv_ * xv_;                                                         \
        o_[4*j+0] = f2bf(s_);                                                          \
        o_[4*j+1] = f2bf(xv_);                                                         \
        o_[4*j+2] = f2bf(x2_);                                                         \
        o_[4*j+3] = f2bf(x2_ * xv_);                                                   \
    }                                                                                  \
    unsigned short* ab_ = smem + (buf) * LDSBUF;                                       \
    *reinterpret_cast<uint4*>(ab_ + aoff0) =                                           \
        make_uint4(pk(o_[0],o_[1]), pk(o_[2],o_[3]), pk(o_[4],o_[5]), pk(o_[6],o_[7]));\
    *reinterpret_cast<uint4*>(ab_ + aoff1) =                                           \
        make_uint4(pk(o_[8],o_[9]), pk(o_[10],o_[11]), pk(o_[12],o_[13]), pk(o_[14],o_[15]));\
} while (0)

    // ---- prologue: tiles 0,1 -> bufs 0,1
    float4 xa = xp[0];
    STAGE_B(0, 0, 0); STAGE_B(0, 0, 1);
    float4 xb = xp[4];
    STAGE_B(1, 1, 0); STAGE_B(1, 1, 1);
    STAGE_A(0, xa);
    STAGE_A(1, xb);
    // B(0) landed (vmcnt: only B(1)'s 4 loads may remain) AND this wave's ds_writes
    // committed (lgkmcnt(0)) before anyone crosses the barrier.
    asm volatile("s_waitcnt vmcnt(4) lgkmcnt(0)" ::: "memory");
    __builtin_amdgcn_s_barrier();

    int cb = 0;
    for (int kt = 0; kt < NKT; ++kt) {
        const unsigned short* sb = smem + cb * LDSBUF;
        const int  nb = (cb >= 1) ? cb - 1 : 2;        // buffer for tile kt+2
        const bool pf = (kt + 2) < NKT;

        bf16x8 av[2][2], bvv[4][2];
        float4 xv = {0.f, 0.f, 0.f, 0.f};

        // ======== phase Q0: A half0 + ALL B; compute acc[0..1][*] ========
        av[0][0] = *reinterpret_cast<const bf16x8*>(sb + aRd + ck0);
        av[0][1] = *reinterpret_cast<const bf16x8*>(sb + aRd + ck1);
        av[1][0] = *reinterpret_cast<const bf16x8*>(sb + aRd + 1024 + ck0);
        av[1][1] = *reinterpret_cast<const bf16x8*>(sb + aRd + 1024 + ck1);
#pragma unroll
        for (int ni = 0; ni < 4; ++ni) {
            bvv[ni][0] = *reinterpret_cast<const bf16x8*>(sb + bRd + ni * 1024 + ck0);
            bvv[ni][1] = *reinterpret_cast<const bf16x8*>(sb + bRd + ni * 1024 + ck1);
        }
        if (pf) { xv = xp[(kt + 2) * 4]; STAGE_B(kt + 2, nb, 0); }
        __builtin_amdgcn_s_barrier();
        asm volatile("s_waitcnt lgkmcnt(0)" ::: "memory");
        __builtin_amdgcn_sched_barrier(0);
        __builtin_amdgcn_s_setprio(1);
#pragma unroll
        for (int kk = 0; kk < 2; ++kk)
#pragma unroll
            for (int mi = 0; mi < 2; ++mi)
#pragma unroll
                for (int ni = 0; ni < 4; ++ni)
                    acc[mi][ni] = __builtin_amdgcn_mfma_f32_16x16x32_bf16(
                        av[mi][kk], bvv[ni][kk], acc[mi][ni], 0, 0, 0);
        __builtin_amdgcn_s_setprio(0);
        __builtin_amdgcn_s_barrier();

        // ======== phase Q1: A half1; B reused from regs; acc[2..3][*] ========
        av[0][0] = *reinterpret_cast<const bf16x8*>(sb + aRd + 4096 + ck0);
        av[0][1] = *reinterpret_cast<const bf16x8*>(sb + aRd + 4096 + ck1);
        av[1][0] = *reinterpret_cast<const bf16x8*>(sb + aRd + 5120 + ck0);
        av[1][1] = *reinterpret_cast<const bf16x8*>(sb + aRd + 5120 + ck1);
        if (pf) {
            STAGE_B(kt + 2, nb, 1);
            STAGE_A(nb, xv);        // compiler inserts the counted x-wait before use;
                                    // writes drain at this wave's lgkmcnt(0) below,
                                    // before the tile-boundary barrier.
        }
        __builtin_amdgcn_s_barrier();
        asm volatile("s_waitcnt lgkmcnt(0)" ::: "memory");
        __builtin_amdgcn_sched_barrier(0);
        __builtin_amdgcn_s_setprio(1);
#pragma unroll
        for (int kk = 0; kk < 2; ++kk)
#pragma unroll
            for (int mi = 0; mi < 2; ++mi)
#pragma unroll
                for (int ni = 0; ni < 4; ++ni)
                    acc[2 + mi][ni] = __builtin_amdgcn_mfma_f32_16x16x32_bf16(
                        av[mi][kk], bvv[ni][kk], acc[2 + mi][ni], 0, 0, 0);
        __builtin_amdgcn_s_setprio(0);

        // ---- tile boundary: B(kt+1) complete (only B(kt+2)'s 4 loads may remain)
        if (kt < NKT - 2) {
            asm volatile("s_waitcnt vmcnt(4)" ::: "memory");
            __builtin_amdgcn_s_barrier();
        } else if (kt == NKT - 2) {
            asm volatile("s_waitcnt vmcnt(0)" ::: "memory");   // drain B(63)
            __builtin_amdgcn_s_barrier();
        }
        cb = (cb == 2) ? 0 : cb + 1;
    }

#undef STAGE_A
#undef STAGE_B

    // ---- epilogue: C/D layout col = lane&15, row = quad*4 + reg
    float bev[4];
#pragma unroll
    for (int ni = 0; ni < 4; ++ni)
        bev[ni] = be[bn * BN + wc * 64 + ni * 16 + l15];

#pragma unroll
    for (int mg = 0; mg < 4; ++mg) {
        const int grow = bm * BM + (mg >> 1) * 64 + wr * 32 + (mg & 1) * 16 + quad * 4;
#pragma unroll
        for (int ni = 0; ni < 4; ++ni) {
            const int gcol = bn * BN + wc * 64 + ni * 16 + l15;
            float* po = out + (size_t)grow * OUT + gcol;
#pragma unroll
            for (int r = 0; r < 4; ++r)
                po[(size_t)r * OUT] = acc[mg][ni][r] + bev[ni];
        }
    }
}

extern "C" void kernel_launch(void* const* d_in, const int* in_sizes, int n_in,
                              void* d_out, int out_size, void* d_ws, size_t ws_size,
                              hipStream_t stream) {
    const float* x    = (const float*)d_in[0];   // [8192,1024]
    const float* W    = (const float*)d_in[1];   // [1024,1024]
    const float* C    = (const float*)d_in[2];   // [1024,1024,4]
    const float* bias = (const float*)d_in[3];   // [1024]
    float* out = (float*)d_out;

    unsigned short* Bb = (unsigned short*)d_ws;                    // 8 MB
    float*          be = (float*)(Bb + (size_t)OUT * KDIM);        // 4 KB

    constexpr int LDS_BYTES = 3 * LDSBUF * 2;                      // 147456 = 144 KB
    static bool inited = false;
    if (!inited) {
        hipFuncSetAttribute(reinterpret_cast<const void*>(&gemm_kan),
                            hipFuncAttributeMaxDynamicSharedMemorySize, LDS_BYTES);
        inited = true;
    }

    prep_b<<<dim3(1024), dim3(256), 0, stream>>>(W, C, bias, Bb, be);

    gemm_kan<<<dim3(256), dim3(512), LDS_BYTES, stream>>>(x, Bb, be, out);
}

// Round 4
// 183.724 us; speedup vs baseline: 1.1076x; 1.1076x over previous
//
#include <hip/hip_runtime.h>
#include <hip/hip_bf16.h>

#define GLOBAL_AS __attribute__((address_space(1)))
#define LDS_AS    __attribute__((address_space(3)))

typedef __bf16 bf16x8 __attribute__((ext_vector_type(8)));
typedef float  f32x4  __attribute__((ext_vector_type(4)));

constexpr int BATCH = 8192;           // M
constexpr int IN    = 1024;
constexpr int OUT   = 1024;           // N
constexpr int KDIM  = IN * 4;         // 4096 (4 "powers" per input)
constexpr int BM = 128, BN = 256, BK = 64;
constexpr int NKT  = KDIM / BK;       // 64 K-tiles
constexpr int LDSBUF = 24576;         // ushort elems per buffer: A 8192 + B 16384 (48 KB)

// round-to-nearest-even float -> bf16 bits (inputs finite)
__device__ __forceinline__ unsigned short f2bf(float f) {
    union { float f; unsigned u; } v; v.f = f;
    unsigned r = v.u + 0x7fffu + ((v.u >> 16) & 1u);
    return (unsigned short)(r >> 16);
}
__device__ __forceinline__ unsigned pk(unsigned short a, unsigned short b) {
    return (unsigned)a | ((unsigned)b << 16);
}

// B-side prep only (A-expansion fused into the gemm).
// B_big[o, 4i+k] = {W[o,i], C[o,i,1..3]} bf16; be[o] = bias[o] + sum_i C[o,i,0].
__global__ __launch_bounds__(256) void prep_b(const float* __restrict__ W,
                                              const float* __restrict__ C,
                                              const float* __restrict__ bias,
                                              unsigned short* __restrict__ Bb,
                                              float* __restrict__ be) {
    const int o = blockIdx.x, t = threadIdx.x;
    const int i0 = t * 4;
    const float4* c4 = reinterpret_cast<const float4*>(C + ((size_t)o * IN + i0) * 4);
    float4 w4 = *reinterpret_cast<const float4*>(W + (size_t)o * IN + i0);
    float wv[4] = {w4.x, w4.y, w4.z, w4.w};
    float s = 0.f;
    unsigned d[8];
#pragma unroll
    for (int j = 0; j < 4; ++j) {
        float4 c = c4[j];
        s += c.x;                                  // x^0 term -> bias
        d[2*j]   = pk(f2bf(wv[j]), f2bf(c.y));
        d[2*j+1] = pk(f2bf(c.z),   f2bf(c.w));
    }
    uint4* dst = reinterpret_cast<uint4*>(Bb + (size_t)o * KDIM + i0 * 4);
    dst[0] = make_uint4(d[0], d[1], d[2], d[3]);
    dst[1] = make_uint4(d[4], d[5], d[6], d[7]);
#pragma unroll
    for (int off = 32; off > 0; off >>= 1) s += __shfl_down(s, off, 64);
    __shared__ float red[4];
    if ((t & 63) == 0) red[t >> 6] = s;
    __syncthreads();
    if (t == 0) be[o] = bias[o] + red[0] + red[1] + red[2] + red[3];
}

// Fused KAN GEMM: C = powers(x)(8192x4096) * B_big(1024x4096)^T + be.
//
// vs Round 3 (which was CORRECT but slow): the A-expansion (x -> {silu,x,x^2,x^3}
// -> swizzled ds_write) is moved from Q1's PRE-barrier region to the tile-BOUNDARY
// shadow (after Q1's MFMA cluster). Round-3's placement put the xv-wait + expf
// chain on every wave's barrier-arrival path AND put the ds_writes into the
// lgkmcnt(0) that gates Q1's MFMAs. Here the expansion overlaps other waves'
// MFMA + this wave's boundary wait, and its ds_writes drain for free at the
// NEXT tile's Q0 lgkmcnt(0) (a full phase later).
//
// Wait bookkeeping (per wave, verified by issue-order):
//   tile kt issues: xld(kt+2), B(kt+2,h0)x2  [Q0];  B(kt+2,h1)x2  [Q1].
//   The compiler's wait for xld(kt+2) before the expansion is vmcnt(4)
//   (4 younger = B(kt+2)x4); being older-inclusive it ALSO completes B(kt+1)x4
//   -- exactly the boundary requirement. Explicit boundary vmcnt(4) kept
//   (trivially satisfied when pf; does the B-drain when !pf at kt==62 -> vmcnt(0)).
// Visibility: writes to buf(kt+2) drain at writer's kt+1-Q0 post-barrier
// lgkmcnt(0), which precedes the barriers readers cross before reading at kt+2.
__global__ __launch_bounds__(512, 2) void gemm_kan(
        const float* __restrict__ x,
        const unsigned short* __restrict__ Bb,
        const float* __restrict__ be,
        float* __restrict__ out) {
    extern __shared__ unsigned short smem[];   // 3 * 24576 ushorts = 144 KB

    const int t    = threadIdx.x;
    const int l    = blockIdx.x;               // 0..255
    const int xcd  = l & 7;
    const int bn   = xcd >> 1;                 // 0..3  (B-panel L2-resident per XCD pair)
    const int bm   = (xcd & 1) * 32 + (l >> 3);// 0..63
    const int lane = t & 63;
    const int wave = t >> 6;                   // 0..7
    const int wr   = wave >> 2;                // 0..1 : M half
    const int wc   = wave & 3;                 // 0..3 : N quarter
    const int l15  = lane & 15;
    const int quad = lane >> 4;
    const int x7   = l15 & 7;

    // ---- B staging (gload_lds, pre-swizzled global source)
    const int rowT = t >> 3;                   // 0..63
    const int chT  = (t & 7) ^ (rowT & 7);
    const unsigned short* bS = Bb + (size_t)(bn * BN + rowT) * KDIM + chT * 8;

    // ---- A staging (reg -> swizzled ds_write): thread t owns row t>>2, x-quad t&3
    const int arow   = t >> 2;                 // 0..127
    const int axi    = t & 3;                  // which 4 of the 16 x's in the tile
    const int aoff0  = arow * 64 + (((axi * 2)     ^ (arow & 7)) * 8);
    const int aoff1  = arow * 64 + (((axi * 2 + 1) ^ (arow & 7)) * 8);
    const float4* xp = reinterpret_cast<const float4*>(
        x + (size_t)(bm * BM + arow) * IN + axi * 4);   // tile kt -> xp[kt*4]

    // ---- ds_read bases (ushort elements)
    const int aRd = (wr * 32 + l15) * 64;            // A region at offset 0
    const int bRd = 8192 + (wc * 64 + l15) * 64;     // B region at offset 8192
    const int ck0 = (quad ^ x7) * 8;
    const int ck1 = ((4 + quad) ^ x7) * 8;

    f32x4 acc[4][4];
    const f32x4 zero = {0.f, 0.f, 0.f, 0.f};
#pragma unroll
    for (int i = 0; i < 4; ++i)
#pragma unroll
        for (int j = 0; j < 4; ++j) acc[i][j] = zero;

#define STAGE_B(tile, buf, h) do {                                                     \
    const unsigned short* s_ = bS + (size_t)(tile) * BK + (size_t)(h) * 128 * KDIM;    \
    unsigned short* d_ = smem + (buf) * LDSBUF + 8192 + (h) * 8192 + t * 8;            \
    __builtin_amdgcn_global_load_lds((const GLOBAL_AS void*)s_, (LDS_AS void*)d_,      \
                                     16, 0, 0);                                        \
    __builtin_amdgcn_global_load_lds((const GLOBAL_AS void*)(s_ + (size_t)64 * KDIM),  \
                                     (LDS_AS void*)(d_ + 4096), 16, 0, 0);             \
} while (0)

    // identical arithmetic to the original prep-A (absmax must not change)
#define STAGE_A(buf, v) do {                                                           \
    float e_[4] = {(v).x, (v).y, (v).z, (v).w};                                        \
    unsigned short o_[16];                                                             \
    _Pragma("unroll")                                                                  \
    for (int j = 0; j < 4; ++j) {                                                      \
        float xv_ = e_[j];                                                             \
        float s_  = xv_ / (1.0f + __expf(-xv_));                                       \
        float x2_ = xv_ * xv_;                                                         \
        o_[4*j+0] = f2bf(s_);                                                          \
        o_[4*j+1] = f2bf(xv_);                                                         \
        o_[4*j+2] = f2bf(x2_);                                                         \
        o_[4*j+3] = f2bf(x2_ * xv_);                                                   \
    }                                                                                  \
    unsigned short* ab_ = smem + (buf) * LDSBUF;                                       \
    *reinterpret_cast<uint4*>(ab_ + aoff0) =                                           \
        make_uint4(pk(o_[0],o_[1]), pk(o_[2],o_[3]), pk(o_[4],o_[5]), pk(o_[6],o_[7]));\
    *reinterpret_cast<uint4*>(ab_ + aoff1) =                                           \
        make_uint4(pk(o_[8],o_[9]), pk(o_[10],o_[11]), pk(o_[12],o_[13]), pk(o_[14],o_[15]));\
} while (0)

    // ---- prologue: issue x0,x1 then B(0)x4 then B(1)x4 (10 vmem ops) ----
    float4 xa = xp[0];
    float4 xb = xp[4];
    STAGE_B(0, 0, 0); STAGE_B(0, 0, 1);
    STAGE_B(1, 1, 0); STAGE_B(1, 1, 1);
    asm volatile("s_waitcnt vmcnt(8)" ::: "memory");   // x0,x1 landed
    STAGE_A(0, xa);
    STAGE_A(1, xb);
    // B(0) landed (B(1)x4 may fly) AND our ds_writes committed before the barrier.
    asm volatile("s_waitcnt vmcnt(4) lgkmcnt(0)" ::: "memory");
    __builtin_amdgcn_s_barrier();
    // loop-entry invariant: outstanding vmem = B(1)x4.

    int cb = 0;
    for (int kt = 0; kt < NKT; ++kt) {
        const unsigned short* sb = smem + cb * LDSBUF;
        const int  nb = (cb >= 1) ? cb - 1 : 2;        // buffer for tile kt+2
        const bool pf = (kt + 2) < NKT;

        bf16x8 av[2][2], bvv[4][2];
        float4 xv = {0.f, 0.f, 0.f, 0.f};

        // ======== phase Q0: A half0 + ALL B; compute acc[0..1][*] ========
        av[0][0] = *reinterpret_cast<const bf16x8*>(sb + aRd + ck0);
        av[0][1] = *reinterpret_cast<const bf16x8*>(sb + aRd + ck1);
        av[1][0] = *reinterpret_cast<const bf16x8*>(sb + aRd + 1024 + ck0);
        av[1][1] = *reinterpret_cast<const bf16x8*>(sb + aRd + 1024 + ck1);
#pragma unroll
        for (int ni = 0; ni < 4; ++ni) {
            bvv[ni][0] = *reinterpret_cast<const bf16x8*>(sb + bRd + ni * 1024 + ck0);
            bvv[ni][1] = *reinterpret_cast<const bf16x8*>(sb + bRd + ni * 1024 + ck1);
        }
        if (pf) { xv = xp[(kt + 2) * 4]; STAGE_B(kt + 2, nb, 0); }
        __builtin_amdgcn_s_barrier();
        asm volatile("s_waitcnt lgkmcnt(0)" ::: "memory");
        __builtin_amdgcn_sched_barrier(0);
        __builtin_amdgcn_s_setprio(1);
#pragma unroll
        for (int kk = 0; kk < 2; ++kk)
#pragma unroll
            for (int mi = 0; mi < 2; ++mi)
#pragma unroll
                for (int ni = 0; ni < 4; ++ni)
                    acc[mi][ni] = __builtin_amdgcn_mfma_f32_16x16x32_bf16(
                        av[mi][kk], bvv[ni][kk], acc[mi][ni], 0, 0, 0);
        __builtin_amdgcn_s_setprio(0);
        __builtin_amdgcn_s_barrier();

        // ======== phase Q1: A half1; B reused from regs; acc[2..3][*] ========
        av[0][0] = *reinterpret_cast<const bf16x8*>(sb + aRd + 4096 + ck0);
        av[0][1] = *reinterpret_cast<const bf16x8*>(sb + aRd + 4096 + ck1);
        av[1][0] = *reinterpret_cast<const bf16x8*>(sb + aRd + 5120 + ck0);
        av[1][1] = *reinterpret_cast<const bf16x8*>(sb + aRd + 5120 + ck1);
        if (pf) STAGE_B(kt + 2, nb, 1);
        __builtin_amdgcn_s_barrier();
        asm volatile("s_waitcnt lgkmcnt(0)" ::: "memory");
        __builtin_amdgcn_sched_barrier(0);
        __builtin_amdgcn_s_setprio(1);
#pragma unroll
        for (int kk = 0; kk < 2; ++kk)
#pragma unroll
            for (int mi = 0; mi < 2; ++mi)
#pragma unroll
                for (int ni = 0; ni < 4; ++ni)
                    acc[2 + mi][ni] = __builtin_amdgcn_mfma_f32_16x16x32_bf16(
                        av[mi][kk], bvv[ni][kk], acc[2 + mi][ni], 0, 0, 0);
        __builtin_amdgcn_s_setprio(0);

        // ---- boundary shadow: A-expansion for tile kt+2 (overlaps other waves'
        // MFMA and this wave's boundary wait; writes drain at next Q0 lgkm(0)).
        if (pf) STAGE_A(nb, xv);   // compiler's xv-wait (vmcnt(4)) also drains B(kt+1)

        if (kt < NKT - 2) {
            asm volatile("s_waitcnt vmcnt(4)" ::: "memory");   // B(kt+1) landed
            __builtin_amdgcn_s_barrier();
        } else if (kt == NKT - 2) {
            asm volatile("s_waitcnt vmcnt(0)" ::: "memory");   // drain B(63)
            __builtin_amdgcn_s_barrier();
        }
        cb = (cb == 2) ? 0 : cb + 1;
    }

#undef STAGE_A
#undef STAGE_B

    // ---- epilogue: C/D layout col = lane&15, row = quad*4 + reg
    float bev[4];
#pragma unroll
    for (int ni = 0; ni < 4; ++ni)
        bev[ni] = be[bn * BN + wc * 64 + ni * 16 + l15];

#pragma unroll
    for (int mg = 0; mg < 4; ++mg) {
        const int grow = bm * BM + (mg >> 1) * 64 + wr * 32 + (mg & 1) * 16 + quad * 4;
#pragma unroll
        for (int ni = 0; ni < 4; ++ni) {
            const int gcol = bn * BN + wc * 64 + ni * 16 + l15;
            float* po = out + (size_t)grow * OUT + gcol;
#pragma unroll
            for (int r = 0; r < 4; ++r)
                po[(size_t)r * OUT] = acc[mg][ni][r] + bev[ni];
        }
    }
}

extern "C" void kernel_launch(void* const* d_in, const int* in_sizes, int n_in,
                              void* d_out, int out_size, void* d_ws, size_t ws_size,
                              hipStream_t stream) {
    const float* x    = (const float*)d_in[0];   // [8192,1024]
    const float* W    = (const float*)d_in[1];   // [1024,1024]
    const float* C    = (const float*)d_in[2];   // [1024,1024,4]
    const float* bias = (const float*)d_in[3];   // [1024]
    float* out = (float*)d_out;

    unsigned short* Bb = (unsigned short*)d_ws;                    // 8 MB
    float*          be = (float*)(Bb + (size_t)OUT * KDIM);        // 4 KB

    constexpr int LDS_BYTES = 3 * LDSBUF * 2;                      // 147456 = 144 KB
    static bool inited = false;
    if (!inited) {
        hipFuncSetAttribute(reinterpret_cast<const void*>(&gemm_kan),
                            hipFuncAttributeMaxDynamicSharedMemorySize, LDS_BYTES);
        inited = true;
    }

    prep_b<<<dim3(1024), dim3(256), 0, stream>>>(W, C, bias, Bb, be);

    gemm_kan<<<dim3(256), dim3(512), LDS_BYTES, stream>>>(x, Bb, be, out);
}

// Round 6
// 173.242 us; speedup vs baseline: 1.1746x; 1.0605x over previous
//
#include <hip/hip_runtime.h>
#include <hip/hip_bf16.h>

#define GLOBAL_AS __attribute__((address_space(1)))
#define LDS_AS    __attribute__((address_space(3)))

typedef __bf16 bf16x8 __attribute__((ext_vector_type(8)));
typedef float  f32x4  __attribute__((ext_vector_type(4)));

constexpr int BATCH = 8192;           // M
constexpr int IN    = 1024;
constexpr int OUT   = 1024;           // N
constexpr int KDIM  = IN * 4;         // 4096 (4 "powers" per input)
constexpr int BM = 128, BN = 256, BK = 64;
constexpr int NKT  = KDIM / BK;       // 64 K-tiles
constexpr int LDSBUF = 24576;         // ushort elems per buffer: A 8192 + B 16384 (48 KB)

// round-to-nearest-even float -> bf16 bits (inputs finite)
__device__ __forceinline__ unsigned short f2bf(float f) {
    union { float f; unsigned u; } v; v.f = f;
    unsigned r = v.u + 0x7fffu + ((v.u >> 16) & 1u);
    return (unsigned short)(r >> 16);
}
__device__ __forceinline__ unsigned pk(unsigned short a, unsigned short b) {
    return (unsigned)a | ((unsigned)b << 16);
}

// Merged prep (round-0 verbatim): blocks [0,8192) build A_big; [8192,9216) build
// B_big + be.  A_big[b,4i+k] = {silu(x),x,x^2,x^3} bf16;
// B_big[o,4i+k] = {W[o,i],C[o,i,1..3]} bf16; be[o] = bias[o] + sum_i C[o,i,0].
__global__ __launch_bounds__(256) void prep(const float* __restrict__ x,
                                            const float* __restrict__ W,
                                            const float* __restrict__ C,
                                            const float* __restrict__ bias,
                                            unsigned short* __restrict__ Ab,
                                            unsigned short* __restrict__ Bb,
                                            float* __restrict__ be) {
    if (blockIdx.x < 8192) {
        int idx = blockIdx.x * 256 + threadIdx.x;      // 8192*1024/4 threads
        float4 v = reinterpret_cast<const float4*>(x)[idx];
        float e0[4] = {v.x, v.y, v.z, v.w};
        unsigned short o[16];
#pragma unroll
        for (int j = 0; j < 4; ++j) {
            float xv = e0[j];
            float s  = xv / (1.0f + __expf(-xv));
            float x2 = xv * xv;
            o[4*j+0] = f2bf(s);
            o[4*j+1] = f2bf(xv);
            o[4*j+2] = f2bf(x2);
            o[4*j+3] = f2bf(x2 * xv);
        }
        uint4 d0 = make_uint4(pk(o[0],o[1]), pk(o[2],o[3]),   pk(o[4],o[5]),   pk(o[6],o[7]));
        uint4 d1 = make_uint4(pk(o[8],o[9]), pk(o[10],o[11]), pk(o[12],o[13]), pk(o[14],o[15]));
        uint4* dst = reinterpret_cast<uint4*>(Ab) + (size_t)idx * 2;
        dst[0] = d0;
        dst[1] = d1;
    } else {
        const int o = blockIdx.x - 8192, t = threadIdx.x;
        const int i0 = t * 4;
        const float4* c4 = reinterpret_cast<const float4*>(C + ((size_t)o * IN + i0) * 4);
        float4 w4 = *reinterpret_cast<const float4*>(W + (size_t)o * IN + i0);
        float wv[4] = {w4.x, w4.y, w4.z, w4.w};
        float s = 0.f;
        unsigned d[8];
#pragma unroll
        for (int j = 0; j < 4; ++j) {
            float4 c = c4[j];
            s += c.x;                                  // x^0 term -> bias
            d[2*j]   = pk(f2bf(wv[j]), f2bf(c.y));
            d[2*j+1] = pk(f2bf(c.z),   f2bf(c.w));
        }
        uint4* dst = reinterpret_cast<uint4*>(Bb + (size_t)o * KDIM + i0 * 4);
        dst[0] = make_uint4(d[0], d[1], d[2], d[3]);
        dst[1] = make_uint4(d[4], d[5], d[6], d[7]);
#pragma unroll
        for (int off = 32; off > 0; off >>= 1) s += __shfl_down(s, off, 64);
        __shared__ float red[4];
        if ((t & 63) == 0) red[t >> 6] = s;
        __syncthreads();
        if (t == 0) be[o] = bias[o] + red[0] + red[1] + red[2] + red[3];
    }
}

// C = A_big(8192x4096) * B_big(1024x4096)^T + be.
//
// UNPINNED depth-2 schedule: 128x256 tile, 8 waves (2M x 4N, wave owns 64x64),
// triple-buffered LDS (3 x 48 KB), ONE raw s_barrier per K-tile, counted
// vmcnt(6) at each boundary (6 gload_lds per tile; prefetch for kt+2 stays in
// flight across 2 barriers; vmcnt never drains to 0 until the tail).
// NO asm lgkmcnt / sched_barrier / setprio: all ds_reads are compiler-emitted,
// so the compiler inserts fine-grained lgkmcnt(N) and freely interleaves
// ds_read with MFMA (removing R1's order-pinning, which m141 shows costs ~40%).
//
// Correctness of the single-barrier scheme:
//  - a wave's ds_reads of buf(kt%3) are lgkm-gated before its MFMAs, which
//    precede its barrier arrival => all reads of a buffer COMPLETE before any
//    wave passes the tile boundary; STAGE(kt+2) into that buffer is issued
//    after the boundary (asm "memory" + s_barrier block motion).
//  - boundary vmcnt(6) leaves kt+2's 6 loads in flight, completes kt+1's.
__global__ __launch_bounds__(512, 2) void gemm_kan(
        const unsigned short* __restrict__ Ab,
        const unsigned short* __restrict__ Bb,
        const float* __restrict__ be,
        float* __restrict__ out) {
    extern __shared__ unsigned short smem[];   // 3 * 24576 ushorts = 144 KB

    const int t    = threadIdx.x;
    const int l    = blockIdx.x;               // 0..255
    const int bm   = l & 63;                   // 0..63
    const int bn   = l >> 6;                   // 0..3
    const int lane = t & 63;
    const int wave = t >> 6;                   // 0..7
    const int wr   = wave >> 2;                // 0..1 : M half
    const int wc   = wave & 3;                 // 0..3 : N quarter
    const int l15  = lane & 15;
    const int quad = lane >> 4;
    const int x7   = l15 & 7;

    // ---- staging: flat 16B-chunk scheme. chunk ch -> LDS offset ch*8 ushorts;
    // row = ch>>3, slot = ch&7, source k-group g = slot ^ (row&7)  (XOR swizzle
    // realized by pre-swizzling the GLOBAL source; LDS dest stays linear).
    const unsigned short* aP[2];
    const unsigned short* bP[4];
#pragma unroll
    for (int i = 0; i < 2; ++i) {
        int ch = i * 512 + t, r = ch >> 3, g = (ch & 7) ^ (r & 7);
        aP[i] = Ab + (size_t)(bm * BM + r) * KDIM + g * 8;
    }
#pragma unroll
    for (int i = 0; i < 4; ++i) {
        int ch = i * 512 + t, r = ch >> 3, g = (ch & 7) ^ (r & 7);
        bP[i] = Bb + (size_t)(bn * BN + r) * KDIM + g * 8;
    }

    // ---- ds_read bases (ushort elements); rows for acc[mi]: +0,+16,+64,+80
    const int aRd = (wr * 32 + l15) * 64;            // A region at offset 0
    const int bRd = 8192 + (wc * 64 + l15) * 64;     // B region at offset 8192

    f32x4 acc[4][4];
    const f32x4 zero = {0.f, 0.f, 0.f, 0.f};
#pragma unroll
    for (int i = 0; i < 4; ++i)
#pragma unroll
        for (int j = 0; j < 4; ++j) acc[i][j] = zero;

#define STAGE(tile, buf) do {                                                          \
    _Pragma("unroll")                                                                  \
    for (int i_ = 0; i_ < 2; ++i_)                                                     \
        __builtin_amdgcn_global_load_lds(                                              \
            (const GLOBAL_AS void*)(aP[i_] + (size_t)(tile) * BK),                     \
            (LDS_AS void*)(smem + (buf) * LDSBUF + (i_ * 512 + t) * 8), 16, 0, 0);     \
    _Pragma("unroll")                                                                  \
    for (int i_ = 0; i_ < 4; ++i_)                                                     \
        __builtin_amdgcn_global_load_lds(                                              \
            (const GLOBAL_AS void*)(bP[i_] + (size_t)(tile) * BK),                     \
            (LDS_AS void*)(smem + (buf) * LDSBUF + 8192 + (i_ * 512 + t) * 8),         \
            16, 0, 0);                                                                 \
} while (0)

    // ---- prologue: tiles 0,1 -> bufs 0,1 (12 loads); tile0 landed, tile1 in flight
    STAGE(0, 0);
    STAGE(1, 1);
    asm volatile("s_waitcnt vmcnt(6)" ::: "memory");
    __builtin_amdgcn_s_barrier();

    int cb = 0;
    for (int kt = 0; kt < NKT; ++kt) {
        const unsigned short* sb = smem + cb * LDSBUF;
        const int nb = (cb >= 1) ? cb - 1 : 2;         // buffer for tile kt+2

        if (kt + 2 < NKT) STAGE(kt + 2, nb);

#pragma unroll
        for (int kk = 0; kk < 2; ++kk) {
            const int ck = ((kk * 4 + quad) ^ x7) * 8;
            bf16x8 af[4], bv[4];
            af[0] = *reinterpret_cast<const bf16x8*>(sb + aRd + ck);
            af[1] = *reinterpret_cast<const bf16x8*>(sb + aRd + 1024 + ck);
            af[2] = *reinterpret_cast<const bf16x8*>(sb + aRd + 4096 + ck);
            af[3] = *reinterpret_cast<const bf16x8*>(sb + aRd + 5120 + ck);
#pragma unroll
            for (int ni = 0; ni < 4; ++ni)
                bv[ni] = *reinterpret_cast<const bf16x8*>(sb + bRd + ni * 1024 + ck);
#pragma unroll
            for (int mi = 0; mi < 4; ++mi)
#pragma unroll
                for (int ni = 0; ni < 4; ++ni)
                    acc[mi][ni] = __builtin_amdgcn_mfma_f32_16x16x32_bf16(
                        af[mi], bv[ni], acc[mi][ni], 0, 0, 0);
        }

        if (kt < NKT - 2) {
            asm volatile("s_waitcnt vmcnt(6)" ::: "memory");   // tile kt+1 landed
            __builtin_amdgcn_s_barrier();
        } else if (kt == NKT - 2) {
            asm volatile("s_waitcnt vmcnt(0)" ::: "memory");   // drain tile 63
            __builtin_amdgcn_s_barrier();
        }
        cb = (cb == 2) ? 0 : cb + 1;
    }

#undef STAGE

    // ---- epilogue: C/D layout col = lane&15, row = quad*4 + reg
    float bev[4];
#pragma unroll
    for (int ni = 0; ni < 4; ++ni)
        bev[ni] = be[bn * BN + wc * 64 + ni * 16 + l15];

#pragma unroll
    for (int mg = 0; mg < 4; ++mg) {
        const int grow = bm * BM + (mg >> 1) * 64 + wr * 32 + (mg & 1) * 16 + quad * 4;
#pragma unroll
        for (int ni = 0; ni < 4; ++ni) {
            const int gcol = bn * BN + wc * 64 + ni * 16 + l15;
            float* po = out + (size_t)grow * OUT + gcol;
#pragma unroll
            for (int r = 0; r < 4; ++r)
                po[(size_t)r * OUT] = acc[mg][ni][r] + bev[ni];
        }
    }
}

extern "C" void kernel_launch(void* const* d_in, const int* in_sizes, int n_in,
                              void* d_out, int out_size, void* d_ws, size_t ws_size,
                              hipStream_t stream) {
    const float* x    = (const float*)d_in[0];   // [8192,1024]
    const float* W    = (const float*)d_in[1];   // [1024,1024]
    const float* C    = (const float*)d_in[2];   // [1024,1024,4]
    const float* bias = (const float*)d_in[3];   // [1024]
    float* out = (float*)d_out;

    unsigned short* Ab = (unsigned short*)d_ws;                    // 64 MB
    unsigned short* Bb = Ab + (size_t)BATCH * KDIM;                // 8 MB
    float*          be = (float*)(Bb + (size_t)OUT * KDIM);        // 4 KB

    constexpr int LDS_BYTES = 3 * LDSBUF * 2;                      // 147456 = 144 KB
    static bool inited = false;
    if (!inited) {
        hipFuncSetAttribute(reinterpret_cast<const void*>(&gemm_kan),
                            hipFuncAttributeMaxDynamicSharedMemorySize, LDS_BYTES);
        inited = true;
    }

    prep<<<dim3(8192 + 1024), dim3(256), 0, stream>>>(x, W, C, bias, Ab, Bb, be);

    gemm_kan<<<dim3(256), dim3(512), LDS_BYTES, stream>>>(Ab, Bb, be, out);
}